// Round 10
// baseline (1028.679 us; speedup 1.0000x reference)
//
#include <hip/hip_runtime.h>

#define N_NODES 100000
#define N_EDGES 1600000
#define IN_SIZE 512
#define HID_SIZE 256
#define OUT_SIZE 40
#define K_STEPS 10
#define ALPHA 0.1f

// radix-by-dst build
#define NCH 250            // chunks; 250 * 6400 = 1.6M
#define CH_E 6400          // edges per chunk (int4-aligned)
#define NBUK 391           // buckets of 256 nodes; 391*256 = 100096 >= N
// deg_out partial histograms
#define NRS 8              // src ranges
#define HRS 12544          // 8 * 12544 = 100352 >= N
#define NCS 16             // src chunks; 16 * 100000 = 1.6M
#define CS_E 100000

typedef _Float16 half8 __attribute__((ext_vector_type(8)));
typedef float f32x4 __attribute__((ext_vector_type(4)));

struct __align__(8) Entry { int s; int d; };

// ---------------- pass 1: per-chunk bucket histogram of dst ----------------
__global__ __launch_bounds__(512) void hist_pass(const int* __restrict__ dst,
                                                 int* __restrict__ cnt) {
    __shared__ int h[NBUK];
    const int t = threadIdx.x, c = blockIdx.x;
    for (int j = t; j < NBUK; j += 512) h[j] = 0;
    __syncthreads();
    const int4* d4 = (const int4*)(dst + c * CH_E);
    for (int i = t; i < CH_E / 4; i += 512) {
        const int4 v = d4[i];
        atomicAdd(&h[v.x >> 8], 1);
        atomicAdd(&h[v.y >> 8], 1);
        atomicAdd(&h[v.z >> 8], 1);
        atomicAdd(&h[v.w >> 8], 1);
    }
    __syncthreads();
    for (int j = t; j < NBUK; j += 512) cnt[c * NBUK + j] = h[j];
}

// ---------------- pass 2: bucket offsets (single block) ----------------
__global__ __launch_bounds__(512) void bucket_scan(const int* __restrict__ cnt,
                                                   int* __restrict__ off,
                                                   int* __restrict__ boff) {
    __shared__ int tot[512];
    const int b = threadIdx.x;
    int s = 0;
    if (b < NBUK)
        for (int c = 0; c < NCH; ++c) s += cnt[c * NBUK + b];
    tot[b] = s;
    __syncthreads();
    for (int o = 1; o < 512; o <<= 1) {
        const int v = (b >= o) ? tot[b - o] : 0;
        __syncthreads();
        tot[b] += v;
        __syncthreads();
    }
    if (b < NBUK) {
        int run = tot[b] - s;           // exclusive prefix
        boff[b] = run;
        for (int c = 0; c < NCH; ++c) { off[c * NBUK + b] = run; run += cnt[c * NBUK + b]; }
        if (b == NBUK - 1) boff[NBUK] = tot[b];
    }
}

// ---------------- pass 3: scatter edges into bucket-grouped ebuf ----------------
__global__ __launch_bounds__(512) void scatter_pass(const int* __restrict__ src,
                                                    const int* __restrict__ dst,
                                                    const int* __restrict__ off,
                                                    Entry* __restrict__ ebuf) {
    __shared__ int cur[NBUK];
    const int t = threadIdx.x, c = blockIdx.x;
    for (int j = t; j < NBUK; j += 512) cur[j] = off[c * NBUK + j];
    __syncthreads();
    const int4* s4 = (const int4*)(src + c * CH_E);
    const int4* d4 = (const int4*)(dst + c * CH_E);
    for (int i = t; i < CH_E / 4; i += 512) {
        const int4 sv = s4[i];
        const int4 dv = d4[i];
        Entry e;
        int p;
        p = atomicAdd(&cur[dv.x >> 8], 1); e.s = sv.x; e.d = dv.x; ebuf[p] = e;
        p = atomicAdd(&cur[dv.y >> 8], 1); e.s = sv.y; e.d = dv.y; ebuf[p] = e;
        p = atomicAdd(&cur[dv.z >> 8], 1); e.s = sv.z; e.d = dv.z; ebuf[p] = e;
        p = atomicAdd(&cur[dv.w >> 8], 1); e.s = sv.w; e.d = dv.w; ebuf[p] = e;
    }
}

// ---------------- pass 4: per-bucket CSR fill + rowp + ndst ----------------
__global__ __launch_bounds__(256) void bucket_csr(const Entry* __restrict__ ebuf,
                                                  const int* __restrict__ boff,
                                                  int* __restrict__ rowp,
                                                  float* __restrict__ ndst,
                                                  int* __restrict__ csr) {
    __shared__ int hist[256];
    __shared__ int pref[256];
    __shared__ int cur[256];
    const int t = threadIdx.x, b = blockIdx.x;
    const int beg = boff[b], end = boff[b + 1];
    hist[t] = 0;
    __syncthreads();
    for (int i = beg + t; i < end; i += 256)
        atomicAdd(&hist[ebuf[i].d & 255], 1);
    __syncthreads();
    const int h = hist[t];
    pref[t] = h;
    __syncthreads();
    for (int o = 1; o < 256; o <<= 1) {
        const int v = (t >= o) ? pref[t - o] : 0;
        __syncthreads();
        pref[t] += v;
        __syncthreads();
    }
    const int val = beg + pref[t] - h;   // exclusive prefix + bucket base
    const int n = (b << 8) + t;
    if (n <= N_NODES) rowp[n] = val;
    if (n < N_NODES) ndst[n] = 1.0f / sqrtf((float)max(h, 1));
    cur[t] = val;
    __syncthreads();
    for (int i = beg + t; i < end; i += 256) {
        const Entry e = ebuf[i];
        const int pos = atomicAdd(&cur[e.d & 255], 1);
        csr[pos] = e.s;
    }
}

// ---------------- deg_out: range x chunk partial histograms ----------------
__global__ __launch_bounds__(512) void degsrc_part(const int* __restrict__ src,
                                                   int* __restrict__ partial) {
    __shared__ int h[HRS];
    const int t = threadIdx.x;
    const int r = blockIdx.x & (NRS - 1);
    const int c = blockIdx.x >> 3;
    const int base = r * HRS;
    for (int j = t; j < HRS; j += 512) h[j] = 0;
    __syncthreads();
    const int4* s4 = (const int4*)(src + (size_t)c * CS_E);
    for (int i = t; i < CS_E / 4; i += 512) {
        const int4 v = s4[i];
        unsigned u;
        u = (unsigned)(v.x - base); if (u < HRS) atomicAdd(&h[u], 1);
        u = (unsigned)(v.y - base); if (u < HRS) atomicAdd(&h[u], 1);
        u = (unsigned)(v.z - base); if (u < HRS) atomicAdd(&h[u], 1);
        u = (unsigned)(v.w - base); if (u < HRS) atomicAdd(&h[u], 1);
    }
    __syncthreads();
    for (int j = t; j < HRS; j += 512) partial[(size_t)c * (NRS * HRS) + base + j] = h[j];
}

__global__ __launch_bounds__(256) void nsrc_reduce(const int* __restrict__ partial,
                                                   float* __restrict__ nsrc) {
    const int n = blockIdx.x * 256 + threadIdx.x;
    int s = 0;
#pragma unroll
    for (int c = 0; c < NCS; ++c) s += partial[(size_t)c * (NRS * HRS) + n];
    if (n < N_NODES) nsrc[n] = 1.0f / sqrtf((float)max(s, 1));
}

// ---------------- prep: W1^T as fp16 [256][512] ----------------
__global__ __launch_bounds__(256) void prep_w1t(const float* __restrict__ W1,
                                                unsigned short* __restrict__ w1t) {
    int idx = blockIdx.x * 256 + threadIdx.x;
    if (idx < IN_SIZE * HID_SIZE) {
        int n = idx >> 9;
        int k = idx & 511;
        _Float16 h = (_Float16)W1[(size_t)k * HID_SIZE + n];
        w1t[idx] = *(unsigned short*)&h;
    }
}

// ---------------- GEMM1: h1 = relu(X @ W1 + b1) in fp16 via MFMA ----------------
__global__ __launch_bounds__(512) void gemm1_f16(const float* __restrict__ X,
                                                 const unsigned short* __restrict__ w1t,
                                                 const float* __restrict__ b1,
                                                 _Float16* __restrict__ h1) {
    __shared__ __align__(16) _Float16 sA[128 * 64];
    __shared__ __align__(16) _Float16 sB[256 * 64];

    const int t    = threadIdx.x;
    const int lane = t & 63;
    const int w    = t >> 6;
    const int wr   = w >> 2;
    const int wc   = w & 3;
    const int n0   = blockIdx.x * 128;

    f32x4 acc[4][4];
#pragma unroll
    for (int i = 0; i < 4; ++i)
#pragma unroll
        for (int j = 0; j < 4; ++j) acc[i][j] = (f32x4)0.f;

    const int lo = lane & 15;
    const int hi = lane >> 4;
    const int l7 = lane & 7;

    for (int kk = 0; kk < IN_SIZE; kk += 64) {
        __syncthreads();
#pragma unroll
        for (int i = 0; i < 2; ++i) {
            int id  = t + i * 512;
            int row = id >> 3;
            int ch  = id & 7;
            int gr  = n0 + row;
            float4 x0 = make_float4(0.f, 0.f, 0.f, 0.f), x1 = x0;
            if (gr < N_NODES) {
                const float* p = X + (size_t)gr * IN_SIZE + kk + ch * 8;
                x0 = ((const float4*)p)[0];
                x1 = ((const float4*)p)[1];
            }
            half8 hv;
            hv[0] = (_Float16)x0.x; hv[1] = (_Float16)x0.y;
            hv[2] = (_Float16)x0.z; hv[3] = (_Float16)x0.w;
            hv[4] = (_Float16)x1.x; hv[5] = (_Float16)x1.y;
            hv[6] = (_Float16)x1.z; hv[7] = (_Float16)x1.w;
            *(half8*)&sA[row * 64 + ((ch ^ (row & 7)) << 3)] = hv;
        }
#pragma unroll
        for (int i = 0; i < 4; ++i) {
            int id = t + i * 512;
            int n  = id >> 3;
            int ch = id & 7;
            uint4 v = *(const uint4*)(w1t + (size_t)n * IN_SIZE + kk + ch * 8);
            *(uint4*)&sB[n * 64 + ((ch ^ (n & 7)) << 3)] = v;
        }
        __syncthreads();
#pragma unroll
        for (int s = 0; s < 2; ++s) {
            const int chs = ((s * 4 + hi) ^ l7) << 3;
            half8 af[4], bf[4];
#pragma unroll
            for (int f = 0; f < 4; ++f)
                af[f] = *(const half8*)&sA[(wr * 64 + f * 16 + lo) * 64 + chs];
#pragma unroll
            for (int f = 0; f < 4; ++f)
                bf[f] = *(const half8*)&sB[(wc * 64 + f * 16 + lo) * 64 + chs];
#pragma unroll
            for (int fi = 0; fi < 4; ++fi)
#pragma unroll
                for (int fj = 0; fj < 4; ++fj)
                    acc[fi][fj] = __builtin_amdgcn_mfma_f32_16x16x32_f16(
                        af[fi], bf[fj], acc[fi][fj], 0, 0, 0);
        }
    }

    float b1v[4];
#pragma unroll
    for (int fj = 0; fj < 4; ++fj) b1v[fj] = b1[wc * 64 + fj * 16 + lo];
#pragma unroll
    for (int fi = 0; fi < 4; ++fi) {
#pragma unroll
        for (int fj = 0; fj < 4; ++fj) {
            const int col = wc * 64 + fj * 16 + lo;
#pragma unroll
            for (int r = 0; r < 4; ++r) {
                int grow = n0 + wr * 64 + fi * 16 + hi * 4 + r;
                if (grow < N_NODES) {
                    float v = acc[fi][fj][r] + b1v[fj];
                    v = fmaxf(v, 0.f);
                    h1[(size_t)grow * HID_SIZE + col] = (_Float16)v;
                }
            }
        }
    }
}

// ---------------- GEMM2: h0 = h1 @ W2 + b2 (fp32 accumulate) ----------------
__global__ __launch_bounds__(256) void gemm2(const _Float16* __restrict__ h1,
                                             const float* __restrict__ W2,
                                             const float* __restrict__ b2,
                                             float* __restrict__ h0) {
    __shared__ __align__(16) float sW2t[40 * 260];
    __shared__ __align__(16) unsigned short sH[64 * 264];

    const int t  = threadIdx.x;
    const int n0 = blockIdx.x * 64;

    for (int idx = t; idx < HID_SIZE * OUT_SIZE; idx += 256) {
        int c = idx / OUT_SIZE;
        int o = idx - c * OUT_SIZE;
        sW2t[o * 260 + c] = W2[idx];
    }
#pragma unroll
    for (int i = 0; i < 8; ++i) {
        int id  = t + i * 256;
        int row = id >> 5;
        int ch  = id & 31;
        uint4 v = make_uint4(0, 0, 0, 0);
        if (n0 + row < N_NODES)
            v = *(const uint4*)(h1 + (size_t)(n0 + row) * HID_SIZE + ch * 8);
        *(uint4*)&sH[row * 264 + ch * 8] = v;
    }
    __syncthreads();

    const int r2 = t >> 2;
    const int q  = t & 3;
    const int o0 = q * 10;
    float acc2[10];
#pragma unroll
    for (int m = 0; m < 10; ++m) acc2[m] = b2[o0 + m];

    for (int c = 0; c < HID_SIZE; c += 8) {
        uint4 hv = *(const uint4*)&sH[r2 * 264 + c];
        const _Float16* hp = (const _Float16*)&hv;
        float f[8];
#pragma unroll
        for (int j = 0; j < 8; ++j) f[j] = (float)hp[j];
#pragma unroll
        for (int m = 0; m < 10; ++m) {
            const float4 w0 = *(const float4*)&sW2t[(o0 + m) * 260 + c];
            const float4 w1 = *(const float4*)&sW2t[(o0 + m) * 260 + c + 4];
            acc2[m] += f[0] * w0.x + f[1] * w0.y + f[2] * w0.z + f[3] * w0.w
                     + f[4] * w1.x + f[5] * w1.y + f[6] * w1.z + f[7] * w1.w;
        }
    }
    if (n0 + r2 < N_NODES) {
        float* dstp = h0 + (size_t)(n0 + r2) * OUT_SIZE + o0;
#pragma unroll
        for (int m = 0; m < 10; ++m) dstp[m] = acc2[m];
    }
}

// ---------------- g0/h0a init, SLICE-MAJOR: [8][N][8 halves] ----------------
// slice s owns channels 5s..5s+4 (halves 5..7 zero-padded).
__global__ __launch_bounds__(256) void g0_init_sliced(const float* __restrict__ h0,
                                                      const float* __restrict__ nsrc,
                                                      _Float16* __restrict__ g,
                                                      _Float16* __restrict__ h0aS) {
    const int n = blockIdx.x * 256 + threadIdx.x;
    if (n >= N_NODES) return;
    const float ns = nsrc[n];
    float v[40];
#pragma unroll
    for (int i = 0; i < 10; ++i) {
        const f32x4 x = *(const f32x4*)(h0 + (size_t)n * OUT_SIZE + i * 4);
        v[i * 4 + 0] = x[0]; v[i * 4 + 1] = x[1];
        v[i * 4 + 2] = x[2]; v[i * 4 + 3] = x[3];
    }
#pragma unroll
    for (int s = 0; s < 8; ++s) {
        half8 gv, av;
#pragma unroll
        for (int k = 0; k < 5; ++k) {
            const float f = v[s * 5 + k];
            gv[k] = (_Float16)(ns * f);
            av[k] = (_Float16)(ALPHA * f);
        }
        gv[5] = (_Float16)0.f; gv[6] = (_Float16)0.f; gv[7] = (_Float16)0.f;
        av[5] = (_Float16)0.f; av[6] = (_Float16)0.f; av[7] = (_Float16)0.f;
        *(half8*)(g    + ((size_t)s * N_NODES + n) * 8) = gv;
        *(half8*)(h0aS + ((size_t)s * N_NODES + n) * 8) = av;
    }
}

// ---------------- APPNP step, XCD-sliced gather ----------------
// grid = 391*8; slice = blockIdx&7 (aligns with XCD round-robin), so each
// XCD's random gathers hit only its own 1.6 MB slice -> L2-resident.
// 1 thread per node; int4 csr loads; half8 gather (5 channels used).
__global__ __launch_bounds__(256) void appnp_sliced(const _Float16* __restrict__ gin,
                                                    const _Float16* __restrict__ h0aS,
                                                    const int* __restrict__ rowp,
                                                    const int* __restrict__ csr,
                                                    const float* __restrict__ nsrc,
                                                    const float* __restrict__ ndst,
                                                    _Float16* __restrict__ gout,
                                                    float* __restrict__ hout,
                                                    int last) {
    const int s = blockIdx.x & 7;
    const int n = (blockIdx.x >> 3) * 256 + threadIdx.x;
    if (n >= N_NODES) return;
    const _Float16* gs = gin + (size_t)s * N_NODES * 8;

    const int beg = rowp[n];
    const int end = rowp[n + 1];

    float a0 = 0.f, a1 = 0.f, a2 = 0.f, a3 = 0.f, a4 = 0.f;
    int e = beg;
    {   // peel to 16B-aligned csr index
        int alim = (beg + 3) & ~3;
        if (alim > end) alim = end;
        for (; e < alim; ++e) {
            const half8 v = *(const half8*)(gs + (size_t)csr[e] * 8);
            a0 += (float)v[0]; a1 += (float)v[1]; a2 += (float)v[2];
            a3 += (float)v[3]; a4 += (float)v[4];
        }
    }
    for (; e + 4 <= end; e += 4) {
        const int4 s4 = *(const int4*)(csr + e);
        const half8 v0 = *(const half8*)(gs + (size_t)s4.x * 8);
        const half8 v1 = *(const half8*)(gs + (size_t)s4.y * 8);
        const half8 v2 = *(const half8*)(gs + (size_t)s4.z * 8);
        const half8 v3 = *(const half8*)(gs + (size_t)s4.w * 8);
        a0 += (float)v0[0] + (float)v1[0] + (float)v2[0] + (float)v3[0];
        a1 += (float)v0[1] + (float)v1[1] + (float)v2[1] + (float)v3[1];
        a2 += (float)v0[2] + (float)v1[2] + (float)v2[2] + (float)v3[2];
        a3 += (float)v0[3] + (float)v1[3] + (float)v2[3] + (float)v3[3];
        a4 += (float)v0[4] + (float)v1[4] + (float)v2[4] + (float)v3[4];
    }
    for (; e < end; ++e) {
        const half8 v = *(const half8*)(gs + (size_t)csr[e] * 8);
        a0 += (float)v[0]; a1 += (float)v[1]; a2 += (float)v[2];
        a3 += (float)v[3]; a4 += (float)v[4];
    }

    const float nd = (1.0f - ALPHA) * ndst[n];
    const half8 ha = *(const half8*)(h0aS + ((size_t)s * N_NODES + n) * 8);
    const float r0 = nd * a0 + (float)ha[0];
    const float r1 = nd * a1 + (float)ha[1];
    const float r2 = nd * a2 + (float)ha[2];
    const float r3 = nd * a3 + (float)ha[3];
    const float r4 = nd * a4 + (float)ha[4];

    if (last) {
        float* o = hout + (size_t)n * OUT_SIZE + s * 5;
        o[0] = r0; o[1] = r1; o[2] = r2; o[3] = r3; o[4] = r4;
    } else {
        const float ns = nsrc[n];
        half8 gv;
        gv[0] = (_Float16)(ns * r0); gv[1] = (_Float16)(ns * r1);
        gv[2] = (_Float16)(ns * r2); gv[3] = (_Float16)(ns * r3);
        gv[4] = (_Float16)(ns * r4);
        gv[5] = (_Float16)0.f; gv[6] = (_Float16)0.f; gv[7] = (_Float16)0.f;
        *(half8*)(gout + ((size_t)s * N_NODES + n) * 8) = gv;
    }
}

// ---------------- launcher ----------------
extern "C" void kernel_launch(void* const* d_in, const int* in_sizes, int n_in,
                              void* d_out, int out_size, void* d_ws, size_t ws_size,
                              hipStream_t stream) {
    const float* X   = (const float*)d_in[0];
    const int*   src = (const int*)d_in[1];
    const int*   dst = (const int*)d_in[2];
    const float* W1  = (const float*)d_in[3];
    const float* b1  = (const float*)d_in[4];
    const float* W2  = (const float*)d_in[5];
    const float* b2  = (const float*)d_in[6];
    float* out = (float*)d_out;

    char* ws = (char*)d_ws;
    size_t off = 0;
    auto alloc = [&](size_t bytes) -> void* {
        void* p = ws + off;
        off = (off + bytes + 255) & ~(size_t)255;
        return p;
    };
    float*    h0   = (float*)alloc((size_t)N_NODES * OUT_SIZE * 4);       // 16 MB
    _Float16* h1   = (_Float16*)alloc((size_t)N_NODES * HID_SIZE * 2);    // 51.2 MB
    _Float16* gSA  = (_Float16*)alloc((size_t)8 * N_NODES * 8 * 2);       // 12.8 MB
    _Float16* gSB  = (_Float16*)alloc((size_t)8 * N_NODES * 8 * 2);       // 12.8 MB
    _Float16* h0aS = (_Float16*)alloc((size_t)8 * N_NODES * 8 * 2);       // 12.8 MB
    Entry* ebuf    = (Entry*)alloc((size_t)N_EDGES * 8);                  // 12.8 MB
    int*   partial = (int*)alloc((size_t)NCS * NRS * HRS * 4);            // 6.5 MB
    float* nsrc = (float*)alloc((size_t)N_NODES * 4);
    float* ndst = (float*)alloc((size_t)N_NODES * 4);
    int* rowp   = (int*)alloc((size_t)(N_NODES + 2) * 4);
    int* csr    = (int*)alloc((size_t)N_EDGES * 4);                       // 6.4 MB
    int* cnt    = (int*)alloc((size_t)NCH * NBUK * 4);
    int* offb   = (int*)alloc((size_t)NCH * NBUK * 4);
    int* boff   = (int*)alloc((size_t)(NBUK + 1) * 4);
    unsigned short* w1t = (unsigned short*)alloc((size_t)IN_SIZE * HID_SIZE * 2);

    // ---- radix CSR build ----
    hist_pass<<<NCH, 512, 0, stream>>>(dst, cnt);
    bucket_scan<<<1, 512, 0, stream>>>(cnt, offb, boff);
    scatter_pass<<<NCH, 512, 0, stream>>>(src, dst, offb, ebuf);
    bucket_csr<<<NBUK, 256, 0, stream>>>(ebuf, boff, rowp, ndst, csr);
    degsrc_part<<<NRS * NCS, 512, 0, stream>>>(src, partial);
    nsrc_reduce<<<(NRS * HRS) / 256, 256, 0, stream>>>(partial, nsrc);

    // ---- MLP (split kernels — measured-good) ----
    prep_w1t<<<(IN_SIZE * HID_SIZE + 255) / 256, 256, 0, stream>>>(W1, w1t);
    gemm1_f16<<<(N_NODES + 127) / 128, 512, 0, stream>>>(X, w1t, b1, h1);
    gemm2<<<(N_NODES + 63) / 64, 256, 0, stream>>>(h1, W2, b2, h0);

    // ---- scaled initial state, slice-major ----
    const int ngrid256 = (N_NODES + 255) / 256;        // 391
    g0_init_sliced<<<ngrid256, 256, 0, stream>>>(h0, nsrc, gSA, h0aS);

    // ---- propagation (grid = ranges x 8 slices; slice = blockIdx&7 -> XCD) ----
    const int sgrid = ngrid256 * 8;                    // 3128
    const _Float16* gin = gSA;
    for (int s = 0; s < K_STEPS; ++s) {
        const int last = (s == K_STEPS - 1) ? 1 : 0;
        _Float16* gout = (s & 1) ? gSA : gSB;
        appnp_sliced<<<sgrid, 256, 0, stream>>>(gin, h0aS, rowp, csr, nsrc, ndst,
                                                gout, out, last);
        gin = gout;
    }
}

// Round 11
// 621.199 us; speedup vs baseline: 1.6560x; 1.6560x over previous
//
#include <hip/hip_runtime.h>

#define N_NODES 100000
#define N_EDGES 1600000
#define IN_SIZE 512
#define HID_SIZE 256
#define OUT_SIZE 40
#define K_STEPS 10
#define ALPHA 0.1f

// radix-by-dst build
#define NCH 250            // chunks; 250 * 6400 = 1.6M
#define CH_E 6400          // edges per chunk (int4-aligned)
#define NBUK 391           // buckets of 256 nodes; 391*256 = 100096 >= N
// deg_out partial histograms
#define NRS 8              // src ranges
#define HRS 12544          // 8 * 12544 = 100352 >= N
#define NCS 16             // src chunks; 16 * 100000 = 1.6M
#define CS_E 100000

typedef _Float16 half8 __attribute__((ext_vector_type(8)));
typedef float f32x4 __attribute__((ext_vector_type(4)));

struct __align__(8) Entry { int s; int d; };

// ---------------- pass 1: per-chunk bucket histogram of dst ----------------
__global__ __launch_bounds__(512) void hist_pass(const int* __restrict__ dst,
                                                 int* __restrict__ cnt) {
    __shared__ int h[NBUK];
    const int t = threadIdx.x, c = blockIdx.x;
    for (int j = t; j < NBUK; j += 512) h[j] = 0;
    __syncthreads();
    const int4* d4 = (const int4*)(dst + c * CH_E);
    for (int i = t; i < CH_E / 4; i += 512) {
        const int4 v = d4[i];
        atomicAdd(&h[v.x >> 8], 1);
        atomicAdd(&h[v.y >> 8], 1);
        atomicAdd(&h[v.z >> 8], 1);
        atomicAdd(&h[v.w >> 8], 1);
    }
    __syncthreads();
    for (int j = t; j < NBUK; j += 512) cnt[c * NBUK + j] = h[j];
}

// ---------------- pass 2: bucket offsets (single block) ----------------
__global__ __launch_bounds__(512) void bucket_scan(const int* __restrict__ cnt,
                                                   int* __restrict__ off,
                                                   int* __restrict__ boff) {
    __shared__ int tot[512];
    const int b = threadIdx.x;
    int s = 0;
    if (b < NBUK)
        for (int c = 0; c < NCH; ++c) s += cnt[c * NBUK + b];
    tot[b] = s;
    __syncthreads();
    for (int o = 1; o < 512; o <<= 1) {
        const int v = (b >= o) ? tot[b - o] : 0;
        __syncthreads();
        tot[b] += v;
        __syncthreads();
    }
    if (b < NBUK) {
        int run = tot[b] - s;           // exclusive prefix
        boff[b] = run;
        for (int c = 0; c < NCH; ++c) { off[c * NBUK + b] = run; run += cnt[c * NBUK + b]; }
        if (b == NBUK - 1) boff[NBUK] = tot[b];
    }
}

// ---------------- pass 3: scatter edges into bucket-grouped ebuf ----------------
__global__ __launch_bounds__(512) void scatter_pass(const int* __restrict__ src,
                                                    const int* __restrict__ dst,
                                                    const int* __restrict__ off,
                                                    Entry* __restrict__ ebuf) {
    __shared__ int cur[NBUK];
    const int t = threadIdx.x, c = blockIdx.x;
    for (int j = t; j < NBUK; j += 512) cur[j] = off[c * NBUK + j];
    __syncthreads();
    const int4* s4 = (const int4*)(src + c * CH_E);
    const int4* d4 = (const int4*)(dst + c * CH_E);
    for (int i = t; i < CH_E / 4; i += 512) {
        const int4 sv = s4[i];
        const int4 dv = d4[i];
        Entry e;
        int p;
        p = atomicAdd(&cur[dv.x >> 8], 1); e.s = sv.x; e.d = dv.x; ebuf[p] = e;
        p = atomicAdd(&cur[dv.y >> 8], 1); e.s = sv.y; e.d = dv.y; ebuf[p] = e;
        p = atomicAdd(&cur[dv.z >> 8], 1); e.s = sv.z; e.d = dv.z; ebuf[p] = e;
        p = atomicAdd(&cur[dv.w >> 8], 1); e.s = sv.w; e.d = dv.w; ebuf[p] = e;
    }
}

// ---------------- pass 4: per-bucket CSR fill + rowp + ndst ----------------
__global__ __launch_bounds__(256) void bucket_csr(const Entry* __restrict__ ebuf,
                                                  const int* __restrict__ boff,
                                                  int* __restrict__ rowp,
                                                  float* __restrict__ ndst,
                                                  int* __restrict__ csr) {
    __shared__ int hist[256];
    __shared__ int pref[256];
    __shared__ int cur[256];
    const int t = threadIdx.x, b = blockIdx.x;
    const int beg = boff[b], end = boff[b + 1];
    hist[t] = 0;
    __syncthreads();
    for (int i = beg + t; i < end; i += 256)
        atomicAdd(&hist[ebuf[i].d & 255], 1);
    __syncthreads();
    const int h = hist[t];
    pref[t] = h;
    __syncthreads();
    for (int o = 1; o < 256; o <<= 1) {
        const int v = (t >= o) ? pref[t - o] : 0;
        __syncthreads();
        pref[t] += v;
        __syncthreads();
    }
    const int val = beg + pref[t] - h;   // exclusive prefix + bucket base
    const int n = (b << 8) + t;
    if (n <= N_NODES) rowp[n] = val;
    if (n < N_NODES) ndst[n] = 1.0f / sqrtf((float)max(h, 1));
    cur[t] = val;
    __syncthreads();
    for (int i = beg + t; i < end; i += 256) {
        const Entry e = ebuf[i];
        const int pos = atomicAdd(&cur[e.d & 255], 1);
        csr[pos] = e.s;
    }
}

// ---------------- deg_out: range x chunk partial histograms ----------------
__global__ __launch_bounds__(512) void degsrc_part(const int* __restrict__ src,
                                                   int* __restrict__ partial) {
    __shared__ int h[HRS];
    const int t = threadIdx.x;
    const int r = blockIdx.x & (NRS - 1);
    const int c = blockIdx.x >> 3;
    const int base = r * HRS;
    for (int j = t; j < HRS; j += 512) h[j] = 0;
    __syncthreads();
    const int4* s4 = (const int4*)(src + (size_t)c * CS_E);
    for (int i = t; i < CS_E / 4; i += 512) {
        const int4 v = s4[i];
        unsigned u;
        u = (unsigned)(v.x - base); if (u < HRS) atomicAdd(&h[u], 1);
        u = (unsigned)(v.y - base); if (u < HRS) atomicAdd(&h[u], 1);
        u = (unsigned)(v.z - base); if (u < HRS) atomicAdd(&h[u], 1);
        u = (unsigned)(v.w - base); if (u < HRS) atomicAdd(&h[u], 1);
    }
    __syncthreads();
    for (int j = t; j < HRS; j += 512) partial[(size_t)c * (NRS * HRS) + base + j] = h[j];
}

__global__ __launch_bounds__(256) void nsrc_reduce(const int* __restrict__ partial,
                                                   float* __restrict__ nsrc) {
    const int n = blockIdx.x * 256 + threadIdx.x;
    int s = 0;
#pragma unroll
    for (int c = 0; c < NCS; ++c) s += partial[(size_t)c * (NRS * HRS) + n];
    if (n < N_NODES) nsrc[n] = 1.0f / sqrtf((float)max(s, 1));
}

// ---------------- prep: W1^T as fp16 [256][512] ----------------
__global__ __launch_bounds__(256) void prep_w1t(const float* __restrict__ W1,
                                                unsigned short* __restrict__ w1t) {
    int idx = blockIdx.x * 256 + threadIdx.x;
    if (idx < IN_SIZE * HID_SIZE) {
        int n = idx >> 9;
        int k = idx & 511;
        _Float16 h = (_Float16)W1[(size_t)k * HID_SIZE + n];
        w1t[idx] = *(unsigned short*)&h;
    }
}

// ---------------- GEMM1 (pipelined): h1 = relu(X @ W1 + b1), fp16 MFMA -------
// Same tile as R6 (BM=128,BN=256,BK=64,8 waves) + register prefetch: next
// K-tile's global loads are issued between LDS-write and the compute barrier,
// so HBM latency hides under the MFMA phase (only change vs R6's gemm1).
__global__ __launch_bounds__(512) void gemm1_f16(const float* __restrict__ X,
                                                 const unsigned short* __restrict__ w1t,
                                                 const float* __restrict__ b1,
                                                 _Float16* __restrict__ h1) {
    __shared__ __align__(16) _Float16 sA[128 * 64];
    __shared__ __align__(16) _Float16 sB[256 * 64];

    const int t    = threadIdx.x;
    const int lane = t & 63;
    const int w    = t >> 6;
    const int wr   = w >> 2;
    const int wc   = w & 3;
    const int n0   = blockIdx.x * 128;

    f32x4 acc[4][4];
#pragma unroll
    for (int i = 0; i < 4; ++i)
#pragma unroll
        for (int j = 0; j < 4; ++j) acc[i][j] = (f32x4)0.f;

    const int lo = lane & 15;
    const int hi = lane >> 4;
    const int l7 = lane & 7;

    // staging maps
    int offA[2]; bool okA[2]; const float* pA[2];
#pragma unroll
    for (int i = 0; i < 2; ++i) {
        const int id  = t + i * 512;
        const int row = id >> 3;
        const int ch  = id & 7;
        offA[i] = row * 64 + ((ch ^ (row & 7)) << 3);
        const int gr = n0 + row;
        okA[i] = (gr < N_NODES);
        pA[i] = X + (size_t)(okA[i] ? gr : 0) * IN_SIZE + ch * 8;
    }
    int offB[4]; const unsigned short* pB[4];
#pragma unroll
    for (int i = 0; i < 4; ++i) {
        const int id = t + i * 512;
        const int n  = id >> 3;
        const int ch = id & 7;
        offB[i] = n * 64 + ((ch ^ (n & 7)) << 3);
        pB[i] = w1t + (size_t)n * IN_SIZE + ch * 8;
    }

    float4 xr[2][2];
#pragma unroll
    for (int i = 0; i < 2; ++i) { xr[i][0] = make_float4(0,0,0,0); xr[i][1] = xr[i][0]; }
    uint4 br[4];

    // prologue: loads for kk=0
#pragma unroll
    for (int i = 0; i < 2; ++i)
        if (okA[i]) { xr[i][0] = ((const float4*)pA[i])[0]; xr[i][1] = ((const float4*)pA[i])[1]; }
#pragma unroll
    for (int i = 0; i < 4; ++i) br[i] = *(const uint4*)pB[i];

    for (int kk = 0; kk < IN_SIZE; kk += 64) {
        __syncthreads();   // previous tile's compute done
        // write staged regs -> LDS (fp32->fp16 convert for A)
#pragma unroll
        for (int i = 0; i < 2; ++i) {
            half8 hv;
            hv[0] = (_Float16)xr[i][0].x; hv[1] = (_Float16)xr[i][0].y;
            hv[2] = (_Float16)xr[i][0].z; hv[3] = (_Float16)xr[i][0].w;
            hv[4] = (_Float16)xr[i][1].x; hv[5] = (_Float16)xr[i][1].y;
            hv[6] = (_Float16)xr[i][1].z; hv[7] = (_Float16)xr[i][1].w;
            *(half8*)&sA[offA[i]] = hv;
        }
#pragma unroll
        for (int i = 0; i < 4; ++i) *(uint4*)&sB[offB[i]] = br[i];
        // issue next tile's loads (in flight across barrier + MFMA)
        if (kk + 64 < IN_SIZE) {
#pragma unroll
            for (int i = 0; i < 2; ++i)
                if (okA[i]) {
                    xr[i][0] = ((const float4*)(pA[i] + kk + 64))[0];
                    xr[i][1] = ((const float4*)(pA[i] + kk + 64))[1];
                }
#pragma unroll
            for (int i = 0; i < 4; ++i) br[i] = *(const uint4*)(pB[i] + kk + 64);
        }
        __syncthreads();
#pragma unroll
        for (int s = 0; s < 2; ++s) {
            const int chs = ((s * 4 + hi) ^ l7) << 3;
            half8 af[4], bf[4];
#pragma unroll
            for (int f = 0; f < 4; ++f)
                af[f] = *(const half8*)&sA[(wr * 64 + f * 16 + lo) * 64 + chs];
#pragma unroll
            for (int f = 0; f < 4; ++f)
                bf[f] = *(const half8*)&sB[(wc * 64 + f * 16 + lo) * 64 + chs];
#pragma unroll
            for (int fi = 0; fi < 4; ++fi)
#pragma unroll
                for (int fj = 0; fj < 4; ++fj)
                    acc[fi][fj] = __builtin_amdgcn_mfma_f32_16x16x32_f16(
                        af[fi], bf[fj], acc[fi][fj], 0, 0, 0);
        }
    }

    float b1v[4];
#pragma unroll
    for (int fj = 0; fj < 4; ++fj) b1v[fj] = b1[wc * 64 + fj * 16 + lo];
#pragma unroll
    for (int fi = 0; fi < 4; ++fi) {
#pragma unroll
        for (int fj = 0; fj < 4; ++fj) {
            const int col = wc * 64 + fj * 16 + lo;
#pragma unroll
            for (int r = 0; r < 4; ++r) {
                int grow = n0 + wr * 64 + fi * 16 + hi * 4 + r;
                if (grow < N_NODES) {
                    float v = acc[fi][fj][r] + b1v[fj];
                    v = fmaxf(v, 0.f);
                    h1[(size_t)grow * HID_SIZE + col] = (_Float16)v;
                }
            }
        }
    }
}

// ---------------- GEMM2: h0 = h1 @ W2 + b2 (fp32 accumulate) ----------------
__global__ __launch_bounds__(256) void gemm2(const _Float16* __restrict__ h1,
                                             const float* __restrict__ W2,
                                             const float* __restrict__ b2,
                                             float* __restrict__ h0) {
    __shared__ __align__(16) float sW2t[40 * 260];
    __shared__ __align__(16) unsigned short sH[64 * 264];

    const int t  = threadIdx.x;
    const int n0 = blockIdx.x * 64;

    for (int idx = t; idx < HID_SIZE * OUT_SIZE; idx += 256) {
        int c = idx / OUT_SIZE;
        int o = idx - c * OUT_SIZE;
        sW2t[o * 260 + c] = W2[idx];
    }
#pragma unroll
    for (int i = 0; i < 8; ++i) {
        int id  = t + i * 256;
        int row = id >> 5;
        int ch  = id & 31;
        uint4 v = make_uint4(0, 0, 0, 0);
        if (n0 + row < N_NODES)
            v = *(const uint4*)(h1 + (size_t)(n0 + row) * HID_SIZE + ch * 8);
        *(uint4*)&sH[row * 264 + ch * 8] = v;
    }
    __syncthreads();

    const int r2 = t >> 2;
    const int q  = t & 3;
    const int o0 = q * 10;
    float acc2[10];
#pragma unroll
    for (int m = 0; m < 10; ++m) acc2[m] = b2[o0 + m];

    for (int c = 0; c < HID_SIZE; c += 8) {
        uint4 hv = *(const uint4*)&sH[r2 * 264 + c];
        const _Float16* hp = (const _Float16*)&hv;
        float f[8];
#pragma unroll
        for (int j = 0; j < 8; ++j) f[j] = (float)hp[j];
#pragma unroll
        for (int m = 0; m < 10; ++m) {
            const float4 w0 = *(const float4*)&sW2t[(o0 + m) * 260 + c];
            const float4 w1 = *(const float4*)&sW2t[(o0 + m) * 260 + c + 4];
            acc2[m] += f[0] * w0.x + f[1] * w0.y + f[2] * w0.z + f[3] * w0.w
                     + f[4] * w1.x + f[5] * w1.y + f[6] * w1.z + f[7] * w1.w;
        }
    }
    if (n0 + r2 < N_NODES) {
        float* dstp = h0 + (size_t)(n0 + r2) * OUT_SIZE + o0;
#pragma unroll
        for (int m = 0; m < 10; ++m) dstp[m] = acc2[m];
    }
}

// ---------------- g0 = nsrc * h0, fp16, rows padded to 64 halves (128B) ------
__global__ __launch_bounds__(320) void g0_init(const float* __restrict__ h0,
                                               const float* __restrict__ nsrc,
                                               _Float16* __restrict__ g) {
    const int tid = threadIdx.x;
    const int ln  = tid / 5;
    const int q   = tid - ln * 5;
    const int n   = blockIdx.x * 64 + ln;
    if (n >= N_NODES) return;
    const float ns = nsrc[n];
    const f32x4 a = *(const f32x4*)(h0 + (size_t)n * OUT_SIZE + q * 8);
    const f32x4 b = *(const f32x4*)(h0 + (size_t)n * OUT_SIZE + q * 8 + 4);
    half8 gv;
    gv[0] = (_Float16)(ns * a[0]); gv[1] = (_Float16)(ns * a[1]);
    gv[2] = (_Float16)(ns * a[2]); gv[3] = (_Float16)(ns * a[3]);
    gv[4] = (_Float16)(ns * b[0]); gv[5] = (_Float16)(ns * b[1]);
    gv[6] = (_Float16)(ns * b[2]); gv[7] = (_Float16)(ns * b[3]);
    *(half8*)(g + (size_t)n * 64 + q * 8) = gv;
}

// ---------------- APPNP step: scaled fp16 state, unweighted gather ----------
// (R6's step3 — measured best: ~36 us/step, ~94% of the 128B-granule roofline)
__global__ __launch_bounds__(320) void appnp_step3(const _Float16* __restrict__ gin,
                                                   const float* __restrict__ h0,
                                                   const int* __restrict__ rowp,
                                                   const int* __restrict__ csr,
                                                   const float* __restrict__ nsrc,
                                                   const float* __restrict__ ndst,
                                                   _Float16* __restrict__ gout,
                                                   float* __restrict__ hout,
                                                   int last) {
    const int tid = threadIdx.x;
    const int ln  = tid / 5;
    const int q   = tid - ln * 5;
    const int n   = blockIdx.x * 64 + ln;
    if (n >= N_NODES) return;

    const int beg = rowp[n];
    const int end = rowp[n + 1];
    const _Float16* gq = gin + q * 8;

    float acc[8];
#pragma unroll
    for (int j = 0; j < 8; ++j) acc[j] = 0.f;

    int e = beg;
    for (; e + 4 <= end; e += 4) {
        const int s0 = csr[e + 0];
        const int s1 = csr[e + 1];
        const int s2 = csr[e + 2];
        const int s3 = csr[e + 3];
        const half8 v0 = *(const half8*)(gq + (size_t)s0 * 64);
        const half8 v1 = *(const half8*)(gq + (size_t)s1 * 64);
        const half8 v2 = *(const half8*)(gq + (size_t)s2 * 64);
        const half8 v3 = *(const half8*)(gq + (size_t)s3 * 64);
#pragma unroll
        for (int j = 0; j < 8; ++j)
            acc[j] += (float)v0[j] + (float)v1[j] + (float)v2[j] + (float)v3[j];
    }
    for (; e < end; ++e) {
        const int s0 = csr[e];
        const half8 v0 = *(const half8*)(gq + (size_t)s0 * 64);
#pragma unroll
        for (int j = 0; j < 8; ++j) acc[j] += (float)v0[j];
    }

    const float nd = (1.0f - ALPHA) * ndst[n];
    const f32x4 h0a = *(const f32x4*)(h0 + (size_t)n * OUT_SIZE + q * 8);
    const f32x4 h0b = *(const f32x4*)(h0 + (size_t)n * OUT_SIZE + q * 8 + 4);
    float r[8];
    r[0] = nd * acc[0] + ALPHA * h0a[0]; r[1] = nd * acc[1] + ALPHA * h0a[1];
    r[2] = nd * acc[2] + ALPHA * h0a[2]; r[3] = nd * acc[3] + ALPHA * h0a[3];
    r[4] = nd * acc[4] + ALPHA * h0b[0]; r[5] = nd * acc[5] + ALPHA * h0b[1];
    r[6] = nd * acc[6] + ALPHA * h0b[2]; r[7] = nd * acc[7] + ALPHA * h0b[3];

    if (last) {
        f32x4 ra, rb;
        ra[0] = r[0]; ra[1] = r[1]; ra[2] = r[2]; ra[3] = r[3];
        rb[0] = r[4]; rb[1] = r[5]; rb[2] = r[6]; rb[3] = r[7];
        *(f32x4*)(hout + (size_t)n * OUT_SIZE + q * 8) = ra;
        *(f32x4*)(hout + (size_t)n * OUT_SIZE + q * 8 + 4) = rb;
    } else {
        const float ns = nsrc[n];
        half8 gv;
#pragma unroll
        for (int j = 0; j < 8; ++j) gv[j] = (_Float16)(ns * r[j]);
        *(half8*)(gout + (size_t)n * 64 + q * 8) = gv;
    }
}

// ---------------- launcher (R6 ordering: MLP first, build second) ------------
extern "C" void kernel_launch(void* const* d_in, const int* in_sizes, int n_in,
                              void* d_out, int out_size, void* d_ws, size_t ws_size,
                              hipStream_t stream) {
    const float* X   = (const float*)d_in[0];
    const int*   src = (const int*)d_in[1];
    const int*   dst = (const int*)d_in[2];
    const float* W1  = (const float*)d_in[3];
    const float* b1  = (const float*)d_in[4];
    const float* W2  = (const float*)d_in[5];
    const float* b2  = (const float*)d_in[6];
    float* out = (float*)d_out;

    char* ws = (char*)d_ws;
    size_t off = 0;
    auto alloc = [&](size_t bytes) -> void* {
        void* p = ws + off;
        off = (off + bytes + 255) & ~(size_t)255;
        return p;
    };
    // persistent
    float* h0 = (float*)alloc((size_t)N_NODES * OUT_SIZE * 4);     // 16 MB
    const size_t mark = off;

    // ---- phase A (MLP) region ----
    unsigned short* w1t = (unsigned short*)alloc((size_t)IN_SIZE * HID_SIZE * 2);  // 256 KB
    _Float16*       h1  = (_Float16*)alloc((size_t)N_NODES * HID_SIZE * 2);        // 51.2 MB

    // ---- phase B region: aliases phase A (w1t/h1 dead after gemm2) ----
    off = mark;
    _Float16* gA = (_Float16*)alloc((size_t)N_NODES * 64 * 2);   // 12.8 MB
    _Float16* gB = (_Float16*)alloc((size_t)N_NODES * 64 * 2);   // 12.8 MB
    // partial (6.5 MB) aliases gA: dead before g0_init writes gA
    int*   partial = (int*)gA;                                   // [NCS][NRS*HRS]
    // ebuf (12.8 MB) aliases gB: dead before step 0 writes gB
    Entry* ebuf    = (Entry*)gB;
    float* nsrc = (float*)alloc((size_t)N_NODES * 4);
    float* ndst = (float*)alloc((size_t)N_NODES * 4);
    int* rowp   = (int*)alloc((size_t)(N_NODES + 2) * 4);
    int* csr    = (int*)alloc((size_t)N_EDGES * 4);              // 6.4 MB
    int* cnt    = (int*)alloc((size_t)NCH * NBUK * 4);           // 391 KB
    int* offb   = (int*)alloc((size_t)NCH * NBUK * 4);           // 391 KB
    int* boff   = (int*)alloc((size_t)(NBUK + 1) * 4);

    const int pgrid = (N_NODES + 63) / 64;             // 1563 (320-thread blocks)

    // ---- phase A: MLP ----
    prep_w1t<<<(IN_SIZE * HID_SIZE + 255) / 256, 256, 0, stream>>>(W1, w1t);
    gemm1_f16<<<(N_NODES + 127) / 128, 512, 0, stream>>>(X, w1t, b1, h1);
    gemm2<<<(N_NODES + 63) / 64, 256, 0, stream>>>(h1, W2, b2, h0);

    // ---- phase B: radix CSR build (no device atomics anywhere) ----
    hist_pass<<<NCH, 512, 0, stream>>>(dst, cnt);
    bucket_scan<<<1, 512, 0, stream>>>(cnt, offb, boff);
    scatter_pass<<<NCH, 512, 0, stream>>>(src, dst, offb, ebuf);
    bucket_csr<<<NBUK, 256, 0, stream>>>(ebuf, boff, rowp, ndst, csr);

    // ---- deg_out -> nsrc (non-atomic partial histograms) ----
    degsrc_part<<<NRS * NCS, 512, 0, stream>>>(src, partial);
    nsrc_reduce<<<(NRS * HRS) / 256, 256, 0, stream>>>(partial, nsrc);

    // ---- scaled initial state (partial dead; gA now live) ----
    g0_init<<<pgrid, 320, 0, stream>>>(h0, nsrc, gA);

    // ---- propagation (ebuf dead; gB now live) ----
    const _Float16* gin = gA;
    for (int s = 0; s < K_STEPS; ++s) {
        const int last = (s == K_STEPS - 1) ? 1 : 0;
        _Float16* gout = (s & 1) ? gA : gB;
        appnp_step3<<<pgrid, 320, 0, stream>>>(gin, h0, rowp, csr, nsrc, ndst,
                                               gout, out, last);
        gin = gout;
    }
}

// Round 12
// 550.312 us; speedup vs baseline: 1.8693x; 1.1288x over previous
//
#include <hip/hip_runtime.h>

#define N_NODES 100000
#define N_EDGES 1600000
#define IN_SIZE 512
#define HID_SIZE 256
#define OUT_SIZE 40
#define K_STEPS 10
#define ALPHA 0.1f

// radix-by-dst build
#define NCH 250            // chunks; 250 * 6400 = 1.6M
#define CH_E 6400          // edges per chunk (int4-aligned)
#define NBUK 391           // buckets of 256 nodes; 391*256 = 100096 >= N
// deg_out partial histograms
#define NRS 8              // src ranges
#define HRS 12544          // 8 * 12544 = 100352 >= N
#define NCS 16             // src chunks; 16 * 100000 = 1.6M
#define CS_E 100000

typedef _Float16 half8 __attribute__((ext_vector_type(8)));
typedef float f32x4 __attribute__((ext_vector_type(4)));

struct __align__(8) Entry { int s; int d; };

// async global->LDS, 16B per lane (LDS dest = wave-uniform base + lane*16)
__device__ inline void gld_lds16(const void* g, void* l) {
    __builtin_amdgcn_global_load_lds(
        (const __attribute__((address_space(1))) void*)g,
        (__attribute__((address_space(3))) void*)l,
        16, 0, 0);
}

// ---------------- pass 1: per-chunk bucket histogram of dst ----------------
__global__ __launch_bounds__(512) void hist_pass(const int* __restrict__ dst,
                                                 int* __restrict__ cnt) {
    __shared__ int h[NBUK];
    const int t = threadIdx.x, c = blockIdx.x;
    for (int j = t; j < NBUK; j += 512) h[j] = 0;
    __syncthreads();
    const int4* d4 = (const int4*)(dst + c * CH_E);
    for (int i = t; i < CH_E / 4; i += 512) {
        const int4 v = d4[i];
        atomicAdd(&h[v.x >> 8], 1);
        atomicAdd(&h[v.y >> 8], 1);
        atomicAdd(&h[v.z >> 8], 1);
        atomicAdd(&h[v.w >> 8], 1);
    }
    __syncthreads();
    for (int j = t; j < NBUK; j += 512) cnt[c * NBUK + j] = h[j];
}

// ---------------- pass 2: bucket offsets (single block) ----------------
__global__ __launch_bounds__(512) void bucket_scan(const int* __restrict__ cnt,
                                                   int* __restrict__ off,
                                                   int* __restrict__ boff) {
    __shared__ int tot[512];
    const int b = threadIdx.x;
    int s = 0;
    if (b < NBUK)
        for (int c = 0; c < NCH; ++c) s += cnt[c * NBUK + b];
    tot[b] = s;
    __syncthreads();
    for (int o = 1; o < 512; o <<= 1) {
        const int v = (b >= o) ? tot[b - o] : 0;
        __syncthreads();
        tot[b] += v;
        __syncthreads();
    }
    if (b < NBUK) {
        int run = tot[b] - s;           // exclusive prefix
        boff[b] = run;
        for (int c = 0; c < NCH; ++c) { off[c * NBUK + b] = run; run += cnt[c * NBUK + b]; }
        if (b == NBUK - 1) boff[NBUK] = tot[b];
    }
}

// ---------------- pass 3: scatter edges into bucket-grouped ebuf ----------------
__global__ __launch_bounds__(512) void scatter_pass(const int* __restrict__ src,
                                                    const int* __restrict__ dst,
                                                    const int* __restrict__ off,
                                                    Entry* __restrict__ ebuf) {
    __shared__ int cur[NBUK];
    const int t = threadIdx.x, c = blockIdx.x;
    for (int j = t; j < NBUK; j += 512) cur[j] = off[c * NBUK + j];
    __syncthreads();
    const int4* s4 = (const int4*)(src + c * CH_E);
    const int4* d4 = (const int4*)(dst + c * CH_E);
    for (int i = t; i < CH_E / 4; i += 512) {
        const int4 sv = s4[i];
        const int4 dv = d4[i];
        Entry e;
        int p;
        p = atomicAdd(&cur[dv.x >> 8], 1); e.s = sv.x; e.d = dv.x; ebuf[p] = e;
        p = atomicAdd(&cur[dv.y >> 8], 1); e.s = sv.y; e.d = dv.y; ebuf[p] = e;
        p = atomicAdd(&cur[dv.z >> 8], 1); e.s = sv.z; e.d = dv.z; ebuf[p] = e;
        p = atomicAdd(&cur[dv.w >> 8], 1); e.s = sv.w; e.d = dv.w; ebuf[p] = e;
    }
}

// ---------------- pass 4: per-bucket CSR fill + rowp + ndst ----------------
__global__ __launch_bounds__(256) void bucket_csr(const Entry* __restrict__ ebuf,
                                                  const int* __restrict__ boff,
                                                  int* __restrict__ rowp,
                                                  float* __restrict__ ndst,
                                                  int* __restrict__ csr) {
    __shared__ int hist[256];
    __shared__ int pref[256];
    __shared__ int cur[256];
    const int t = threadIdx.x, b = blockIdx.x;
    const int beg = boff[b], end = boff[b + 1];
    hist[t] = 0;
    __syncthreads();
    for (int i = beg + t; i < end; i += 256)
        atomicAdd(&hist[ebuf[i].d & 255], 1);
    __syncthreads();
    const int h = hist[t];
    pref[t] = h;
    __syncthreads();
    for (int o = 1; o < 256; o <<= 1) {
        const int v = (t >= o) ? pref[t - o] : 0;
        __syncthreads();
        pref[t] += v;
        __syncthreads();
    }
    const int val = beg + pref[t] - h;   // exclusive prefix + bucket base
    const int n = (b << 8) + t;
    if (n <= N_NODES) rowp[n] = val;
    if (n < N_NODES) ndst[n] = 1.0f / sqrtf((float)max(h, 1));
    cur[t] = val;
    __syncthreads();
    for (int i = beg + t; i < end; i += 256) {
        const Entry e = ebuf[i];
        const int pos = atomicAdd(&cur[e.d & 255], 1);
        csr[pos] = e.s;
    }
}

// ---------------- deg_out: range x chunk partial histograms ----------------
__global__ __launch_bounds__(512) void degsrc_part(const int* __restrict__ src,
                                                   int* __restrict__ partial) {
    __shared__ int h[HRS];
    const int t = threadIdx.x;
    const int r = blockIdx.x & (NRS - 1);
    const int c = blockIdx.x >> 3;
    const int base = r * HRS;
    for (int j = t; j < HRS; j += 512) h[j] = 0;
    __syncthreads();
    const int4* s4 = (const int4*)(src + (size_t)c * CS_E);
    for (int i = t; i < CS_E / 4; i += 512) {
        const int4 v = s4[i];
        unsigned u;
        u = (unsigned)(v.x - base); if (u < HRS) atomicAdd(&h[u], 1);
        u = (unsigned)(v.y - base); if (u < HRS) atomicAdd(&h[u], 1);
        u = (unsigned)(v.z - base); if (u < HRS) atomicAdd(&h[u], 1);
        u = (unsigned)(v.w - base); if (u < HRS) atomicAdd(&h[u], 1);
    }
    __syncthreads();
    for (int j = t; j < HRS; j += 512) partial[(size_t)c * (NRS * HRS) + base + j] = h[j];
}

__global__ __launch_bounds__(256) void nsrc_reduce(const int* __restrict__ partial,
                                                   float* __restrict__ nsrc) {
    const int n = blockIdx.x * 256 + threadIdx.x;
    int s = 0;
#pragma unroll
    for (int c = 0; c < NCS; ++c) s += partial[(size_t)c * (NRS * HRS) + n];
    if (n < N_NODES) nsrc[n] = 1.0f / sqrtf((float)max(s, 1));
}

// ---------------- prep: W1 as 8 pre-swizzled per-K-tile LDS images ----------
// w1tp[kt][p]: p = n*64 + ((ch ^ (n&7))<<3) + j  holds  W1[kt*64 + ch*8 + j][n]
// so a linear 32KB copy of tile kt reproduces the swizzled sB image exactly.
__global__ __launch_bounds__(256) void prep_w1tp(const float* __restrict__ W1,
                                                 unsigned short* __restrict__ w1tp) {
    int idx = blockIdx.x * 256 + threadIdx.x;
    if (idx < IN_SIZE * HID_SIZE) {
        const int kt  = idx >> 14;         // 0..7
        const int p   = idx & 16383;
        const int n   = p >> 6;            // 0..255
        const int off = p & 63;
        const int j   = off & 7;
        const int ch  = (off >> 3) ^ (n & 7);
        const int kg  = kt * 64 + ch * 8 + j;   // 0..511
        _Float16 h = (_Float16)W1[(size_t)kg * HID_SIZE + n];
        w1tp[idx] = *(unsigned short*)&h;
    }
}

// ---------------- GEMM1: h1 = relu(X @ W1 + b1), fp16 MFMA -------------------
// R6 structure; ONLY change: B-tile staged via async global_load_lds (16B/lane)
// from the pre-swizzled w1tp image (no VGPR roundtrip; DMA overlaps A staging).
__global__ __launch_bounds__(512) void gemm1_f16(const float* __restrict__ X,
                                                 const unsigned short* __restrict__ w1tp,
                                                 const float* __restrict__ b1,
                                                 _Float16* __restrict__ h1) {
    __shared__ __align__(16) _Float16 sA[128 * 64];
    __shared__ __align__(16) _Float16 sB[256 * 64];

    const int t    = threadIdx.x;
    const int lane = t & 63;
    const int w    = t >> 6;
    const int wr   = w >> 2;
    const int wc   = w & 3;
    const int n0   = blockIdx.x * 128;

    f32x4 acc[4][4];
#pragma unroll
    for (int i = 0; i < 4; ++i)
#pragma unroll
        for (int j = 0; j < 4; ++j) acc[i][j] = (f32x4)0.f;

    const int lo = lane & 15;
    const int hi = lane >> 4;
    const int l7 = lane & 7;

    for (int kk = 0; kk < IN_SIZE; kk += 64) {
        __syncthreads();
        // ---- B: async DMA of the pre-swizzled 32KB tile image ----
        {
            const unsigned short* gsrc = w1tp + ((size_t)(kk >> 6) << 14);
#pragma unroll
            for (int i = 0; i < 4; ++i) {
                const int c = t + i * 512;      // 16B chunk id 0..2047
                gld_lds16(gsrc + c * 8, &sB[c * 8]);
            }
        }
        // ---- A: X[128 rows][kk..kk+63] -> fp16, swizzled (manual, as R6) ----
#pragma unroll
        for (int i = 0; i < 2; ++i) {
            int id  = t + i * 512;
            int row = id >> 3;
            int ch  = id & 7;
            int gr  = n0 + row;
            float4 x0 = make_float4(0.f, 0.f, 0.f, 0.f), x1 = x0;
            if (gr < N_NODES) {
                const float* p = X + (size_t)gr * IN_SIZE + kk + ch * 8;
                x0 = ((const float4*)p)[0];
                x1 = ((const float4*)p)[1];
            }
            half8 hv;
            hv[0] = (_Float16)x0.x; hv[1] = (_Float16)x0.y;
            hv[2] = (_Float16)x0.z; hv[3] = (_Float16)x0.w;
            hv[4] = (_Float16)x1.x; hv[5] = (_Float16)x1.y;
            hv[6] = (_Float16)x1.z; hv[7] = (_Float16)x1.w;
            *(half8*)&sA[row * 64 + ((ch ^ (row & 7)) << 3)] = hv;
        }
        __syncthreads();   // compiler drains vmcnt (DMA) + lgkmcnt here
        // ---- compute: 2 k-slices of 32 ----
#pragma unroll
        for (int s = 0; s < 2; ++s) {
            const int chs = ((s * 4 + hi) ^ l7) << 3;
            half8 af[4], bf[4];
#pragma unroll
            for (int f = 0; f < 4; ++f)
                af[f] = *(const half8*)&sA[(wr * 64 + f * 16 + lo) * 64 + chs];
#pragma unroll
            for (int f = 0; f < 4; ++f)
                bf[f] = *(const half8*)&sB[(wc * 64 + f * 16 + lo) * 64 + chs];
#pragma unroll
            for (int fi = 0; fi < 4; ++fi)
#pragma unroll
                for (int fj = 0; fj < 4; ++fj)
                    acc[fi][fj] = __builtin_amdgcn_mfma_f32_16x16x32_f16(
                        af[fi], bf[fj], acc[fi][fj], 0, 0, 0);
        }
    }

    float b1v[4];
#pragma unroll
    for (int fj = 0; fj < 4; ++fj) b1v[fj] = b1[wc * 64 + fj * 16 + lo];
#pragma unroll
    for (int fi = 0; fi < 4; ++fi) {
#pragma unroll
        for (int fj = 0; fj < 4; ++fj) {
            const int col = wc * 64 + fj * 16 + lo;
#pragma unroll
            for (int r = 0; r < 4; ++r) {
                int grow = n0 + wr * 64 + fi * 16 + hi * 4 + r;
                if (grow < N_NODES) {
                    float v = acc[fi][fj][r] + b1v[fj];
                    v = fmaxf(v, 0.f);
                    h1[(size_t)grow * HID_SIZE + col] = (_Float16)v;
                }
            }
        }
    }
}

// ---------------- GEMM2: h0 = h1 @ W2 + b2 (fp32 accumulate) ----------------
__global__ __launch_bounds__(256) void gemm2(const _Float16* __restrict__ h1,
                                             const float* __restrict__ W2,
                                             const float* __restrict__ b2,
                                             float* __restrict__ h0) {
    __shared__ __align__(16) float sW2t[40 * 260];
    __shared__ __align__(16) unsigned short sH[64 * 264];

    const int t  = threadIdx.x;
    const int n0 = blockIdx.x * 64;

    for (int idx = t; idx < HID_SIZE * OUT_SIZE; idx += 256) {
        int c = idx / OUT_SIZE;
        int o = idx - c * OUT_SIZE;
        sW2t[o * 260 + c] = W2[idx];
    }
#pragma unroll
    for (int i = 0; i < 8; ++i) {
        int id  = t + i * 256;
        int row = id >> 5;
        int ch  = id & 31;
        uint4 v = make_uint4(0, 0, 0, 0);
        if (n0 + row < N_NODES)
            v = *(const uint4*)(h1 + (size_t)(n0 + row) * HID_SIZE + ch * 8);
        *(uint4*)&sH[row * 264 + ch * 8] = v;
    }
    __syncthreads();

    const int r2 = t >> 2;
    const int q  = t & 3;
    const int o0 = q * 10;
    float acc2[10];
#pragma unroll
    for (int m = 0; m < 10; ++m) acc2[m] = b2[o0 + m];

    for (int c = 0; c < HID_SIZE; c += 8) {
        uint4 hv = *(const uint4*)&sH[r2 * 264 + c];
        const _Float16* hp = (const _Float16*)&hv;
        float f[8];
#pragma unroll
        for (int j = 0; j < 8; ++j) f[j] = (float)hp[j];
#pragma unroll
        for (int m = 0; m < 10; ++m) {
            const float4 w0 = *(const float4*)&sW2t[(o0 + m) * 260 + c];
            const float4 w1 = *(const float4*)&sW2t[(o0 + m) * 260 + c + 4];
            acc2[m] += f[0] * w0.x + f[1] * w0.y + f[2] * w0.z + f[3] * w0.w
                     + f[4] * w1.x + f[5] * w1.y + f[6] * w1.z + f[7] * w1.w;
        }
    }
    if (n0 + r2 < N_NODES) {
        float* dstp = h0 + (size_t)(n0 + r2) * OUT_SIZE + o0;
#pragma unroll
        for (int m = 0; m < 10; ++m) dstp[m] = acc2[m];
    }
}

// ---------------- g0 = nsrc * h0, fp16, rows padded to 64 halves (128B) ------
__global__ __launch_bounds__(320) void g0_init(const float* __restrict__ h0,
                                               const float* __restrict__ nsrc,
                                               _Float16* __restrict__ g) {
    const int tid = threadIdx.x;
    const int ln  = tid / 5;
    const int q   = tid - ln * 5;
    const int n   = blockIdx.x * 64 + ln;
    if (n >= N_NODES) return;
    const float ns = nsrc[n];
    const f32x4 a = *(const f32x4*)(h0 + (size_t)n * OUT_SIZE + q * 8);
    const f32x4 b = *(const f32x4*)(h0 + (size_t)n * OUT_SIZE + q * 8 + 4);
    half8 gv;
    gv[0] = (_Float16)(ns * a[0]); gv[1] = (_Float16)(ns * a[1]);
    gv[2] = (_Float16)(ns * a[2]); gv[3] = (_Float16)(ns * a[3]);
    gv[4] = (_Float16)(ns * b[0]); gv[5] = (_Float16)(ns * b[1]);
    gv[6] = (_Float16)(ns * b[2]); gv[7] = (_Float16)(ns * b[3]);
    *(half8*)(g + (size_t)n * 64 + q * 8) = gv;
}

// ---------------- APPNP step: scaled fp16 state, unweighted gather ----------
// (R6's step3 — measured best: ~36 us/step, ~sector roofline)
__global__ __launch_bounds__(320) void appnp_step3(const _Float16* __restrict__ gin,
                                                   const float* __restrict__ h0,
                                                   const int* __restrict__ rowp,
                                                   const int* __restrict__ csr,
                                                   const float* __restrict__ nsrc,
                                                   const float* __restrict__ ndst,
                                                   _Float16* __restrict__ gout,
                                                   float* __restrict__ hout,
                                                   int last) {
    const int tid = threadIdx.x;
    const int ln  = tid / 5;
    const int q   = tid - ln * 5;
    const int n   = blockIdx.x * 64 + ln;
    if (n >= N_NODES) return;

    const int beg = rowp[n];
    const int end = rowp[n + 1];
    const _Float16* gq = gin + q * 8;

    float acc[8];
#pragma unroll
    for (int j = 0; j < 8; ++j) acc[j] = 0.f;

    int e = beg;
    for (; e + 4 <= end; e += 4) {
        const int s0 = csr[e + 0];
        const int s1 = csr[e + 1];
        const int s2 = csr[e + 2];
        const int s3 = csr[e + 3];
        const half8 v0 = *(const half8*)(gq + (size_t)s0 * 64);
        const half8 v1 = *(const half8*)(gq + (size_t)s1 * 64);
        const half8 v2 = *(const half8*)(gq + (size_t)s2 * 64);
        const half8 v3 = *(const half8*)(gq + (size_t)s3 * 64);
#pragma unroll
        for (int j = 0; j < 8; ++j)
            acc[j] += (float)v0[j] + (float)v1[j] + (float)v2[j] + (float)v3[j];
    }
    for (; e < end; ++e) {
        const int s0 = csr[e];
        const half8 v0 = *(const half8*)(gq + (size_t)s0 * 64);
#pragma unroll
        for (int j = 0; j < 8; ++j) acc[j] += (float)v0[j];
    }

    const float nd = (1.0f - ALPHA) * ndst[n];
    const f32x4 h0a = *(const f32x4*)(h0 + (size_t)n * OUT_SIZE + q * 8);
    const f32x4 h0b = *(const f32x4*)(h0 + (size_t)n * OUT_SIZE + q * 8 + 4);
    float r[8];
    r[0] = nd * acc[0] + ALPHA * h0a[0]; r[1] = nd * acc[1] + ALPHA * h0a[1];
    r[2] = nd * acc[2] + ALPHA * h0a[2]; r[3] = nd * acc[3] + ALPHA * h0a[3];
    r[4] = nd * acc[4] + ALPHA * h0b[0]; r[5] = nd * acc[5] + ALPHA * h0b[1];
    r[6] = nd * acc[6] + ALPHA * h0b[2]; r[7] = nd * acc[7] + ALPHA * h0b[3];

    if (last) {
        f32x4 ra, rb;
        ra[0] = r[0]; ra[1] = r[1]; ra[2] = r[2]; ra[3] = r[3];
        rb[0] = r[4]; rb[1] = r[5]; rb[2] = r[6]; rb[3] = r[7];
        *(f32x4*)(hout + (size_t)n * OUT_SIZE + q * 8) = ra;
        *(f32x4*)(hout + (size_t)n * OUT_SIZE + q * 8 + 4) = rb;
    } else {
        const float ns = nsrc[n];
        half8 gv;
#pragma unroll
        for (int j = 0; j < 8; ++j) gv[j] = (_Float16)(ns * r[j]);
        *(half8*)(gout + (size_t)n * 64 + q * 8) = gv;
    }
}

// ---------------- launcher (R6 ordering: MLP first, build second) ------------
extern "C" void kernel_launch(void* const* d_in, const int* in_sizes, int n_in,
                              void* d_out, int out_size, void* d_ws, size_t ws_size,
                              hipStream_t stream) {
    const float* X   = (const float*)d_in[0];
    const int*   src = (const int*)d_in[1];
    const int*   dst = (const int*)d_in[2];
    const float* W1  = (const float*)d_in[3];
    const float* b1  = (const float*)d_in[4];
    const float* W2  = (const float*)d_in[5];
    const float* b2  = (const float*)d_in[6];
    float* out = (float*)d_out;

    char* ws = (char*)d_ws;
    size_t off = 0;
    auto alloc = [&](size_t bytes) -> void* {
        void* p = ws + off;
        off = (off + bytes + 255) & ~(size_t)255;
        return p;
    };
    // persistent
    float* h0 = (float*)alloc((size_t)N_NODES * OUT_SIZE * 4);     // 16 MB
    const size_t mark = off;

    // ---- phase A (MLP) region ----
    unsigned short* w1tp = (unsigned short*)alloc((size_t)IN_SIZE * HID_SIZE * 2); // 256 KB
    _Float16*       h1   = (_Float16*)alloc((size_t)N_NODES * HID_SIZE * 2);       // 51.2 MB

    // ---- phase B region: aliases phase A (w1tp/h1 dead after gemm2) ----
    off = mark;
    _Float16* gA = (_Float16*)alloc((size_t)N_NODES * 64 * 2);   // 12.8 MB
    _Float16* gB = (_Float16*)alloc((size_t)N_NODES * 64 * 2);   // 12.8 MB
    // partial (6.5 MB) aliases gA: dead before g0_init writes gA
    int*   partial = (int*)gA;                                   // [NCS][NRS*HRS]
    // ebuf (12.8 MB) aliases gB: dead before step 0 writes gB
    Entry* ebuf    = (Entry*)gB;
    float* nsrc = (float*)alloc((size_t)N_NODES * 4);
    float* ndst = (float*)alloc((size_t)N_NODES * 4);
    int* rowp   = (int*)alloc((size_t)(N_NODES + 2) * 4);
    int* csr    = (int*)alloc((size_t)N_EDGES * 4);              // 6.4 MB
    int* cnt    = (int*)alloc((size_t)NCH * NBUK * 4);           // 391 KB
    int* offb   = (int*)alloc((size_t)NCH * NBUK * 4);           // 391 KB
    int* boff   = (int*)alloc((size_t)(NBUK + 1) * 4);

    const int pgrid = (N_NODES + 63) / 64;             // 1563 (320-thread blocks)

    // ---- phase A: MLP ----
    prep_w1tp<<<(IN_SIZE * HID_SIZE + 255) / 256, 256, 0, stream>>>(W1, w1tp);
    gemm1_f16<<<(N_NODES + 127) / 128, 512, 0, stream>>>(X, w1tp, b1, h1);
    gemm2<<<(N_NODES + 63) / 64, 256, 0, stream>>>(h1, W2, b2, h0);

    // ---- phase B: radix CSR build (no device atomics anywhere) ----
    hist_pass<<<NCH, 512, 0, stream>>>(dst, cnt);
    bucket_scan<<<1, 512, 0, stream>>>(cnt, offb, boff);
    scatter_pass<<<NCH, 512, 0, stream>>>(src, dst, offb, ebuf);
    bucket_csr<<<NBUK, 256, 0, stream>>>(ebuf, boff, rowp, ndst, csr);

    // ---- deg_out -> nsrc (non-atomic partial histograms) ----
    degsrc_part<<<NRS * NCS, 512, 0, stream>>>(src, partial);
    nsrc_reduce<<<(NRS * HRS) / 256, 256, 0, stream>>>(partial, nsrc);

    // ---- scaled initial state (partial dead; gA now live) ----
    g0_init<<<pgrid, 320, 0, stream>>>(h0, nsrc, gA);

    // ---- propagation (ebuf dead; gB now live) ----
    const _Float16* gin = gA;
    for (int s = 0; s < K_STEPS; ++s) {
        const int last = (s == K_STEPS - 1) ? 1 : 0;
        _Float16* gout = (s & 1) ? gA : gB;
        appnp_step3<<<pgrid, 320, 0, stream>>>(gin, h0, rowp, csr, nsrc, ndst,
                                               gout, out, last);
        gin = gout;
    }
}